// Round 1
// baseline (1951.051 us; speedup 1.0000x reference)
//
#include <hip/hip_runtime.h>

#define TT  128
#define CC  256
#define VV  25
#define KK  3
#define GG  9
#define LL  9
#define NCC 60
#define CINN 3
#define TV  (TT*VV)            // 3200
#define TVP ((TT+GG-1)*VV)     // 3400 (8 pad frames + 128 real frames)

// ---------------- small prep kernels ----------------

__global__ void k_al(const float* __restrict__ A, const float* __restrict__ imp,
                     float* __restrict__ Al) {
    int i = blockIdx.x * 256 + threadIdx.x;
    if (i < LL*KK*VV*VV) Al[i] = A[i % (KK*VV*VV)] * imp[i];
}

// WtT[l][o][g*256+c] = Wt[l][o][c][g]
__global__ void k_wtt(const float* __restrict__ Wt, float* __restrict__ WtT) {
    int i = blockIdx.x * 256 + threadIdx.x;
    if (i >= LL*CC*CC*GG) return;
    int kk = i % (CC*GG);
    int o  = (i / (CC*GG)) % CC;
    int l  = i / (CC*CC*GG);
    int g = kk >> 8, c = kk & 255;
    WtT[i] = Wt[((size_t)(l*CC + o)*CC + c)*GG + g];
}

// ---------------- input stage: LN_in + fcn_in ----------------

__global__ __launch_bounds__(256) void k_h0(const float* __restrict__ x,
                                            const float* __restrict__ lnw,
                                            const float* __restrict__ lnb,
                                            const float* __restrict__ Win,
                                            const float* __restrict__ bin,
                                            float* __restrict__ H) {
    int t = blockIdx.x, tid = threadIdx.x;
    __shared__ float sx[CINN*VV];
    __shared__ float sh[CINN*VV];
    if (tid < CINN*VV)
        sx[tid] = x[(size_t)(tid/VV)*TV + t*VV + (tid%VV)];
    __syncthreads();
    float s = 0.f, q = 0.f;
    for (int i = 0; i < CINN*VV; i++) { float v = sx[i]; s += v; q += v*v; }
    float m  = s * (1.f/75.f);
    float var = q * (1.f/75.f) - m*m;
    float rs = rsqrtf(var + 1e-5f);
    if (tid < CINN*VV)
        sh[tid] = (sx[tid]-m)*rs*lnw[tid] + lnb[tid];
    __syncthreads();
    int c = tid;
    float w0 = Win[c*3+0], w1 = Win[c*3+1], w2 = Win[c*3+2], b = bin[c];
    for (int v = 0; v < VV; v++) {
        float acc = b + w0*sh[v] + w1*sh[VV+v] + w2*sh[2*VV+v];
        H[(size_t)c*TV + t*VV + v] = acc;
    }
}

// ---------------- GEMM1: Y = Wg[l] @ H + bg[l]  (M x 3200, K inner) ----------------

__global__ __launch_bounds__(256) void k_gemm1(const float* __restrict__ A,
                                               const float* __restrict__ B,
                                               const float* __restrict__ bias,
                                               float* __restrict__ C,
                                               int Kdim) {
    __shared__ __align__(16) float As[16][64];
    __shared__ __align__(16) float Bs[16][64];
    const int tid = threadIdx.x;
    const int tx = tid & 15, ty = tid >> 4;
    const int n0 = blockIdx.x * 64, m0 = blockIdx.y * 64;
    const int arow = tid >> 2, acol = (tid & 3) << 2;
    const int brow = tid >> 6, bcol = tid & 63;
    float acc[4][4] = {};
    for (int k0 = 0; k0 < Kdim; k0 += 16) {
        float4 av = *(const float4*)(A + (size_t)(m0+arow)*Kdim + k0 + acol);
        As[acol+0][arow] = av.x; As[acol+1][arow] = av.y;
        As[acol+2][arow] = av.z; As[acol+3][arow] = av.w;
        #pragma unroll
        for (int i = 0; i < 4; i++)
            Bs[brow+4*i][bcol] = B[(size_t)(k0+brow+4*i)*TV + n0 + bcol];
        __syncthreads();
        #pragma unroll
        for (int kk = 0; kk < 16; kk++) {
            float4 a4 = *(const float4*)(&As[kk][ty<<2]);
            float4 b4 = *(const float4*)(&Bs[kk][tx<<2]);
            float a[4] = {a4.x,a4.y,a4.z,a4.w};
            float b[4] = {b4.x,b4.y,b4.z,b4.w};
            #pragma unroll
            for (int i = 0; i < 4; i++)
                #pragma unroll
                for (int j = 0; j < 4; j++)
                    acc[i][j] = fmaf(a[i], b[j], acc[i][j]);
        }
        __syncthreads();
    }
    #pragma unroll
    for (int i = 0; i < 4; i++) {
        float bi = bias[m0 + (ty<<2) + i];
        #pragma unroll
        for (int j = 0; j < 4; j++)
            C[(size_t)(m0+(ty<<2)+i)*TV + n0 + (tx<<2) + j] = acc[i][j] + bi;
    }
}

// ---------------- GEMM2 (tcn): TC = WtT[l] @ Ushift + bt[l] ----------------
// K = 2304 = g-major (g*256+c); B[g*256+c][t*25+v] = U[c][(t+8-g)*25+v]

__global__ __launch_bounds__(256) void k_gemm2(const float* __restrict__ A,
                                               const float* __restrict__ U,
                                               const float* __restrict__ bias,
                                               float* __restrict__ C) {
    __shared__ __align__(16) float As[16][64];
    __shared__ __align__(16) float Bs[16][64];
    const int tid = threadIdx.x;
    const int tx = tid & 15, ty = tid >> 4;
    const int n0 = blockIdx.x * 64, m0 = blockIdx.y * 64;
    const int arow = tid >> 2, acol = (tid & 3) << 2;
    const int brow = tid >> 6, bcol = tid & 63;
    const int Kdim = CC*GG; // 2304
    float acc[4][4] = {};
    for (int k0 = 0; k0 < Kdim; k0 += 16) {
        float4 av = *(const float4*)(A + (size_t)(m0+arow)*Kdim + k0 + acol);
        As[acol+0][arow] = av.x; As[acol+1][arow] = av.y;
        As[acol+2][arow] = av.z; As[acol+3][arow] = av.w;
        int g = k0 >> 8;                       // whole k-tile lies in one g block
        int urow0 = k0 - (g<<8) + brow;        // c index base
        int ucol  = n0 + bcol + (GG-1-g)*VV;   // uniform column shift
        #pragma unroll
        for (int i = 0; i < 4; i++)
            Bs[brow+4*i][bcol] = U[(size_t)(urow0+4*i)*TVP + ucol];
        __syncthreads();
        #pragma unroll
        for (int kk = 0; kk < 16; kk++) {
            float4 a4 = *(const float4*)(&As[kk][ty<<2]);
            float4 b4 = *(const float4*)(&Bs[kk][tx<<2]);
            float a[4] = {a4.x,a4.y,a4.z,a4.w};
            float b[4] = {b4.x,b4.y,b4.z,b4.w};
            #pragma unroll
            for (int i = 0; i < 4; i++)
                #pragma unroll
                for (int j = 0; j < 4; j++)
                    acc[i][j] = fmaf(a[i], b[j], acc[i][j]);
        }
        __syncthreads();
    }
    #pragma unroll
    for (int i = 0; i < 4; i++) {
        float bi = bias[m0 + (ty<<2) + i];
        #pragma unroll
        for (int j = 0; j < 4; j++)
            C[(size_t)(m0+(ty<<2)+i)*TV + n0 + (tx<<2) + j] = acc[i][j] + bi;
    }
}

// ---------------- block reduce (sum, sumsq) over 256 threads ----------------

__device__ __forceinline__ void blk_reduce2(float& s, float& q, float* red) {
    #pragma unroll
    for (int off = 32; off; off >>= 1) {
        s += __shfl_down(s, off);
        q += __shfl_down(q, off);
    }
    int lane = threadIdx.x & 63, w = threadIdx.x >> 6;
    if (lane == 0) { red[w] = s; red[4+w] = q; }
    __syncthreads();
    s = red[0]+red[1]+red[2]+red[3];
    q = red[4]+red[5]+red[6]+red[7];
}

// ---------------- adjacency contraction + LN1 + ReLU -> U (with pad frames) ----------------

__global__ __launch_bounds__(256) void k_adj(const float* __restrict__ Y,
                                             const float* __restrict__ Al,
                                             const float* __restrict__ lnw,
                                             const float* __restrict__ lnb,
                                             float* __restrict__ U) {
    int bid = blockIdx.x, tid = threadIdx.x;
    if (bid >= TT) {               // pad frames: u = relu(ln1_b)
        int tp = bid - TT;         // 0..7
        int c = tid;
        for (int v = 0; v < VV; v++)
            U[(size_t)c*TVP + tp*VV + v] = fmaxf(lnb[c*VV+v], 0.f);
        return;
    }
    __shared__ float sAl[KK*VV*VV];   // 1875
    __shared__ float sY[CC*VV];       // 6400
    __shared__ float red[8];
    int t = bid, c = tid;
    for (int i = tid; i < KK*VV*VV; i += 256) sAl[i] = Al[i];
    float z[VV];
    #pragma unroll
    for (int w = 0; w < VV; w++) z[w] = 0.f;
    for (int k = 0; k < KK; k++) {
        __syncthreads();
        for (int i = tid; i < CC*VV; i += 256)
            sY[i] = Y[(size_t)(k*CC + i/VV)*TV + t*VV + (i%VV)];
        __syncthreads();
        for (int v = 0; v < VV; v++) {
            float yv = sY[c*VV+v];
            const float* alr = &sAl[(k*VV+v)*VV];
            #pragma unroll
            for (int w = 0; w < VV; w++)
                z[w] = fmaf(yv, alr[w], z[w]);
        }
    }
    float s = 0.f, q = 0.f;
    #pragma unroll
    for (int w = 0; w < VV; w++) { s += z[w]; q += z[w]*z[w]; }
    blk_reduce2(s, q, red);
    float m = s * (1.f/6400.f);
    float var = q * (1.f/6400.f) - m*m;
    float rs = rsqrtf(var + 1e-5f);
    for (int w = 0; w < VV; w++) {
        float u = (z[w]-m)*rs*lnw[c*VV+w] + lnb[c*VV+w];
        U[(size_t)c*TVP + (t+GG-1)*VV + w] = fmaxf(u, 0.f);
    }
}

// ---------------- LN2 + delayed residual + ReLU ----------------

__global__ __launch_bounds__(256) void k_ln2(const float* __restrict__ TC,
                                             const float* __restrict__ lnw,
                                             const float* __restrict__ lnb,
                                             const float* __restrict__ Hin,
                                             float* __restrict__ Hout) {
    int t = blockIdx.x, c = threadIdx.x;
    __shared__ float red[8];
    float v[VV];
    float s = 0.f, q = 0.f;
    #pragma unroll
    for (int i = 0; i < VV; i++) {
        v[i] = TC[(size_t)c*TV + t*VV + i];
        s += v[i]; q += v[i]*v[i];
    }
    blk_reduce2(s, q, red);
    float m = s * (1.f/6400.f);
    float var = q * (1.f/6400.f) - m*m;
    float rs = rsqrtf(var + 1e-5f);
    #pragma unroll
    for (int i = 0; i < VV; i++) {
        float r = (t >= 4) ? Hin[(size_t)c*TV + (t-4)*VV + i] : 0.f;
        float o = (v[i]-m)*rs*lnw[c*VV+i] + lnb[c*VV+i] + r;
        Hout[(size_t)c*TV + t*VV + i] = fmaxf(o, 0.f);
    }
}

// ---------------- pool + classifier ----------------

__global__ __launch_bounds__(256) void k_out(const float* __restrict__ H,
                                             const float* __restrict__ Wout,
                                             const float* __restrict__ bout,
                                             float* __restrict__ out) {
    int t = blockIdx.x, tid = threadIdx.x;
    __shared__ float sp[CC];
    float s = 0.f;
    for (int v = 0; v < VV; v++) s += H[(size_t)tid*TV + t*VV + v];
    sp[tid] = s * (1.f/VV);
    __syncthreads();
    if (tid < NCC) {
        float acc = bout[tid];
        for (int c = 0; c < CC; c++) acc = fmaf(Wout[tid*CC+c], sp[c], acc);
        out[t*NCC + tid] = acc;
    }
}

// ---------------- launch ----------------

extern "C" void kernel_launch(void* const* d_in, const int* in_sizes, int n_in,
                              void* d_out, int out_size, void* d_ws, size_t ws_size,
                              hipStream_t stream) {
    const float* x    = (const float*)d_in[0];
    const float* A    = (const float*)d_in[1];
    const float* lniw = (const float*)d_in[2];
    const float* lnib = (const float*)d_in[3];
    const float* Win  = (const float*)d_in[4];
    const float* bin  = (const float*)d_in[5];
    const float* Wg   = (const float*)d_in[6];
    const float* bg   = (const float*)d_in[7];
    const float* ln1w = (const float*)d_in[8];
    const float* ln1b = (const float*)d_in[9];
    const float* Wt   = (const float*)d_in[10];
    const float* bt   = (const float*)d_in[11];
    const float* ln2w = (const float*)d_in[12];
    const float* ln2b = (const float*)d_in[13];
    const float* imp  = (const float*)d_in[14];
    const float* Wout = (const float*)d_in[15];
    const float* bout = (const float*)d_in[16];
    float* out = (float*)d_out;

    float* ws = (float*)d_ws;
    size_t off = 0;
    auto alloc = [&](size_t n) { float* p = ws + off; off += (n + 255) & ~(size_t)255; return p; };
    float* Al  = alloc(LL*KK*VV*VV);
    float* WtT = alloc((size_t)LL*CC*CC*GG);
    float* H0  = alloc((size_t)CC*TV);
    float* H1  = alloc((size_t)CC*TV);
    float* Y   = alloc((size_t)KK*CC*TV);
    float* U   = alloc((size_t)CC*TVP);
    float* TC  = alloc((size_t)CC*TV);
    (void)ws_size; (void)in_sizes; (void)n_in; (void)out_size;

    k_al<<<(LL*KK*VV*VV + 255)/256, 256, 0, stream>>>(A, imp, Al);
    k_wtt<<<((LL*CC*CC*GG) + 255)/256, 256, 0, stream>>>(Wt, WtT);
    k_h0<<<TT, 256, 0, stream>>>(x, lniw, lnib, Win, bin, H0);

    float* Hin = H0; float* Hout = H1;
    for (int l = 0; l < LL; l++) {
        k_gemm1<<<dim3(TV/64, (KK*CC)/64), 256, 0, stream>>>(
            Wg + (size_t)l*KK*CC*CC, Hin, bg + l*KK*CC, Y, CC);
        k_adj<<<TT + GG - 1, 256, 0, stream>>>(
            Y, Al + l*KK*VV*VV, ln1w + l*CC*VV, ln1b + l*CC*VV, U);
        k_gemm2<<<dim3(TV/64, CC/64), 256, 0, stream>>>(
            WtT + (size_t)l*CC*CC*GG, U, bt + l*CC, TC);
        k_ln2<<<TT, 256, 0, stream>>>(
            TC, ln2w + l*CC*VV, ln2b + l*CC*VV, Hin, Hout);
        float* tmp = Hin; Hin = Hout; Hout = tmp;
    }
    k_out<<<TT, 256, 0, stream>>>(Hin, Wout, bout, out);
}

// Round 2
// 1028.227 us; speedup vs baseline: 1.8975x; 1.8975x over previous
//
#include <hip/hip_runtime.h>

#define TT  128
#define CC  256
#define VV  25
#define KK  3
#define GG  9
#define LL  9
#define NCC 60
#define CINN 3
#define TV  (TT*VV)            // 3200
#define TVP ((TT+GG-1)*VV)     // 3400 rows of U^T (200 pad rows + 3200 real)

typedef __attribute__((ext_vector_type(8))) short bf16x8;
typedef __attribute__((ext_vector_type(4))) float f32x4;

__device__ __forceinline__ unsigned short f2bf(float f) {
    union { float f; unsigned u; } a; a.f = f;
    unsigned r = a.u + 0x7fff + ((a.u >> 16) & 1);
    return (unsigned short)(r >> 16);
}

__device__ __forceinline__ bf16x8 ld8(const unsigned short* p) {
    return *(const bf16x8*)p;
}

// ---------------- prep kernels ----------------

__global__ void k_al(const float* __restrict__ A, const float* __restrict__ imp,
                     float* __restrict__ Al) {
    int i = blockIdx.x * 256 + threadIdx.x;
    if (i < LL*KK*VV*VV) Al[i] = A[i % (KK*VV*VV)] * imp[i];
}

__global__ void k_cvt(const float* __restrict__ src, unsigned short* __restrict__ dst, int n) {
    int i = blockIdx.x * 256 + threadIdx.x;
    if (i < n) dst[i] = f2bf(src[i]);
}

// WtTb[l][o][g*256+c] = bf16(Wt[l][o][c][g])
__global__ void k_wtt(const float* __restrict__ Wt, unsigned short* __restrict__ WtTb) {
    int i = blockIdx.x * 256 + threadIdx.x;
    if (i >= LL*CC*CC*GG) return;
    int kk = i % (CC*GG);
    int o  = (i / (CC*GG)) % CC;
    int l  = i / (CC*CC*GG);
    int g = kk >> 8, c = kk & 255;
    WtTb[i] = f2bf(Wt[((size_t)(l*CC + o)*CC + c)*GG + g]);
}

// ---------------- input stage: LN_in + fcn_in ----------------

__global__ __launch_bounds__(256) void k_h0(const float* __restrict__ x,
                                            const float* __restrict__ lnw,
                                            const float* __restrict__ lnb,
                                            const float* __restrict__ Win,
                                            const float* __restrict__ bin,
                                            float* __restrict__ H,
                                            unsigned short* __restrict__ Hbt) {
    int t = blockIdx.x, tid = threadIdx.x;
    __shared__ float sx[CINN*VV];
    __shared__ float sh[CINN*VV];
    if (tid < CINN*VV)
        sx[tid] = x[(size_t)(tid/VV)*TV + t*VV + (tid%VV)];
    __syncthreads();
    float s = 0.f, q = 0.f;
    for (int i = 0; i < CINN*VV; i++) { float v = sx[i]; s += v; q += v*v; }
    float m  = s * (1.f/75.f);
    float var = q * (1.f/75.f) - m*m;
    float rs = rsqrtf(var + 1e-5f);
    if (tid < CINN*VV)
        sh[tid] = (sx[tid]-m)*rs*lnw[tid] + lnb[tid];
    __syncthreads();
    int c = tid;
    float w0 = Win[c*3+0], w1 = Win[c*3+1], w2 = Win[c*3+2], b = bin[c];
    #pragma unroll
    for (int v = 0; v < VV; v++) {
        float acc = b + w0*sh[v] + w1*sh[VV+v] + w2*sh[2*VV+v];
        H[(size_t)c*TV + t*VV + v] = acc;
        Hbt[(size_t)(t*VV + v)*CC + c] = f2bf(acc);   // coalesced across c
    }
}

// ---------------- MFMA GEMM: C = A(bf16, MxK) @ B + bias ----------------
// B supplied transposed: row n of Bt (length 256 shorts) holds B[k...][n].
// SHIFT=1 (tcn): k = g*256+c; B^T row = n + (8-g)*25, col = c.

template<int SHIFT, int KDIM>
__global__ __launch_bounds__(256) void k_gemm(const unsigned short* __restrict__ A,
                                              const unsigned short* __restrict__ Bt,
                                              const float* __restrict__ bias,
                                              float* __restrict__ C) {
    const int tid = threadIdx.x;
    const int wave = tid >> 6, lane = tid & 63;
    const int quad = lane >> 4, l16 = lane & 15;
    const int m0 = blockIdx.y * 64 + (wave & 1) * 32;
    const int n0 = blockIdx.x * 64 + (wave >> 1) * 32;
    const unsigned short* abase = A + (size_t)(m0 + l16) * KDIM + quad * 8;
    f32x4 acc00 = {}, acc01 = {}, acc10 = {}, acc11 = {};
    #pragma unroll 4
    for (int k0 = 0; k0 < KDIM; k0 += 32) {
        bf16x8 a0 = ld8(abase + k0);
        bf16x8 a1 = ld8(abase + k0 + 16 * KDIM);
        int row = SHIFT ? (n0 + l16 + (GG - 1 - (k0 >> 8)) * VV) : (n0 + l16);
        const unsigned short* bbase = Bt + (size_t)row * CC + (k0 & 255) + quad * 8;
        bf16x8 b0 = ld8(bbase);
        bf16x8 b1 = ld8(bbase + 16 * CC);
        acc00 = __builtin_amdgcn_mfma_f32_16x16x32_bf16(a0, b0, acc00, 0, 0, 0);
        acc01 = __builtin_amdgcn_mfma_f32_16x16x32_bf16(a0, b1, acc01, 0, 0, 0);
        acc10 = __builtin_amdgcn_mfma_f32_16x16x32_bf16(a1, b0, acc10, 0, 0, 0);
        acc11 = __builtin_amdgcn_mfma_f32_16x16x32_bf16(a1, b1, acc11, 0, 0, 0);
    }
    const int r0 = m0 + quad * 4;
    const int col = n0 + l16;
    #pragma unroll
    for (int r = 0; r < 4; r++) {
        float b0 = bias[r0 + r], b1 = bias[r0 + 16 + r];
        C[(size_t)(r0 + r) * TV + col]           = acc00[r] + b0;
        C[(size_t)(r0 + r) * TV + col + 16]      = acc01[r] + b0;
        C[(size_t)(r0 + 16 + r) * TV + col]      = acc10[r] + b1;
        C[(size_t)(r0 + 16 + r) * TV + col + 16] = acc11[r] + b1;
    }
}

// ---------------- block reduce (sum, sumsq) ----------------

__device__ __forceinline__ void blk_reduce2(float& s, float& q, float* red) {
    #pragma unroll
    for (int off = 32; off; off >>= 1) {
        s += __shfl_down(s, off);
        q += __shfl_down(q, off);
    }
    int lane = threadIdx.x & 63, w = threadIdx.x >> 6;
    if (lane == 0) { red[w] = s; red[4+w] = q; }
    __syncthreads();
    s = red[0]+red[1]+red[2]+red[3];
    q = red[4]+red[5]+red[6]+red[7];
}

// ---------------- adjacency contraction + LN1 + ReLU -> U^T bf16 ----------------

__global__ __launch_bounds__(256) void k_adj(const float* __restrict__ Y,
                                             const float* __restrict__ Al,
                                             const float* __restrict__ lnw,
                                             const float* __restrict__ lnb,
                                             unsigned short* __restrict__ Ut) {
    int bid = blockIdx.x, c = threadIdx.x;
    if (bid >= TT) {               // pad rows: relu(ln1_b)
        int tp = bid - TT;
        #pragma unroll
        for (int v = 0; v < VV; v++)
            Ut[(size_t)(tp*VV + v)*CC + c] = f2bf(fmaxf(lnb[c*VV+v], 0.f));
        return;
    }
    __shared__ float sY[CC*VV];
    __shared__ float red[8];
    int t = bid;
    float z[VV] = {};
    for (int k = 0; k < KK; k++) {
        __syncthreads();
        for (int i = c; i < CC*VV; i += 256)
            sY[i] = Y[(size_t)(k*CC + i/VV)*TV + t*VV + (i%VV)];
        __syncthreads();
        float y[VV];
        #pragma unroll
        for (int v = 0; v < VV; v++) y[v] = sY[c*VV+v];
        #pragma unroll
        for (int v = 0; v < VV; v++) {
            const float* alr = Al + (k*VV + v)*VV;   // wave-uniform -> s_load
            #pragma unroll
            for (int w = 0; w < VV; w++)
                z[w] = fmaf(y[v], alr[w], z[w]);
        }
    }
    float s = 0.f, q = 0.f;
    #pragma unroll
    for (int w = 0; w < VV; w++) { s += z[w]; q += z[w]*z[w]; }
    blk_reduce2(s, q, red);
    float m = s * (1.f/6400.f);
    float var = q * (1.f/6400.f) - m*m;
    float rs = rsqrtf(var + 1e-5f);
    #pragma unroll
    for (int w = 0; w < VV; w++) {
        float u = (z[w]-m)*rs*lnw[c*VV+w] + lnb[c*VV+w];
        Ut[(size_t)((t+GG-1)*VV + w)*CC + c] = f2bf(fmaxf(u, 0.f));   // coalesced across c
    }
}

// ---------------- LN2 + delayed residual + ReLU -> H fp32 + H^T bf16 ----------------

__global__ __launch_bounds__(256) void k_ln2(const float* __restrict__ TC,
                                             const float* __restrict__ lnw,
                                             const float* __restrict__ lnb,
                                             const float* __restrict__ Hin,
                                             float* __restrict__ Hout,
                                             unsigned short* __restrict__ Hbt) {
    int t = blockIdx.x, tid = threadIdx.x;
    __shared__ float sv[CC*VV];
    __shared__ float red[8];
    float vals[VV];
    float s = 0.f, q = 0.f;
    #pragma unroll
    for (int j = 0; j < VV; j++) {
        int i = tid + j*256;                 // linear i = c*25+v, coalesced-ish loads
        int cc = i / VV, vv = i % VV;
        float xv = TC[(size_t)cc*TV + t*VV + vv];
        vals[j] = xv; s += xv; q += xv*xv;
    }
    blk_reduce2(s, q, red);
    float m = s * (1.f/6400.f);
    float var = q * (1.f/6400.f) - m*m;
    float rs = rsqrtf(var + 1e-5f);
    #pragma unroll
    for (int j = 0; j < VV; j++) {
        int i = tid + j*256;
        int cc = i / VV, vv = i % VV;
        float r = (t >= 4) ? Hin[(size_t)cc*TV + (t-4)*VV + vv] : 0.f;
        float o = fmaxf((vals[j]-m)*rs*lnw[i] + lnb[i] + r, 0.f);
        Hout[(size_t)cc*TV + t*VV + vv] = o;
        sv[i] = o;
    }
    __syncthreads();
    int c = tid;
    #pragma unroll
    for (int v = 0; v < VV; v++)
        Hbt[(size_t)(t*VV + v)*CC + c] = f2bf(sv[c*VV+v]);   // coalesced across c
}

// ---------------- pool + classifier ----------------

__global__ __launch_bounds__(256) void k_out(const float* __restrict__ H,
                                             const float* __restrict__ Wout,
                                             const float* __restrict__ bout,
                                             float* __restrict__ out) {
    int t = blockIdx.x, tid = threadIdx.x;
    __shared__ float sp[CC];
    float s = 0.f;
    for (int v = 0; v < VV; v++) s += H[(size_t)tid*TV + t*VV + v];
    sp[tid] = s * (1.f/VV);
    __syncthreads();
    if (tid < NCC) {
        float acc = bout[tid];
        for (int c = 0; c < CC; c++) acc = fmaf(Wout[tid*CC+c], sp[c], acc);
        out[t*NCC + tid] = acc;
    }
}

// ---------------- launch ----------------

extern "C" void kernel_launch(void* const* d_in, const int* in_sizes, int n_in,
                              void* d_out, int out_size, void* d_ws, size_t ws_size,
                              hipStream_t stream) {
    const float* x    = (const float*)d_in[0];
    const float* A    = (const float*)d_in[1];
    const float* lniw = (const float*)d_in[2];
    const float* lnib = (const float*)d_in[3];
    const float* Win  = (const float*)d_in[4];
    const float* bin  = (const float*)d_in[5];
    const float* Wg   = (const float*)d_in[6];
    const float* bg   = (const float*)d_in[7];
    const float* ln1w = (const float*)d_in[8];
    const float* ln1b = (const float*)d_in[9];
    const float* Wt   = (const float*)d_in[10];
    const float* bt   = (const float*)d_in[11];
    const float* ln2w = (const float*)d_in[12];
    const float* ln2b = (const float*)d_in[13];
    const float* imp  = (const float*)d_in[14];
    const float* Wout = (const float*)d_in[15];
    const float* bout = (const float*)d_in[16];
    float* out = (float*)d_out;

    float* ws = (float*)d_ws;
    size_t off = 0;
    auto alloc = [&](size_t n) { float* p = ws + off; off += (n + 255) & ~(size_t)255; return p; };
    float* Al  = alloc(LL*KK*VV*VV);
    float* Y   = alloc((size_t)KK*CC*TV);
    float* TC  = alloc((size_t)CC*TV);
    float* H0  = alloc((size_t)CC*TV);
    float* H1  = alloc((size_t)CC*TV);
    unsigned short* Wgb  = (unsigned short*)alloc((size_t)LL*KK*CC*CC/2);
    unsigned short* WtTb = (unsigned short*)alloc((size_t)LL*CC*CC*GG/2);
    unsigned short* Hbt  = (unsigned short*)alloc((size_t)TV*CC/2);
    unsigned short* Ut   = (unsigned short*)alloc((size_t)TVP*CC/2);
    (void)ws_size; (void)in_sizes; (void)n_in; (void)out_size;

    k_al<<<(LL*KK*VV*VV + 255)/256, 256, 0, stream>>>(A, imp, Al);
    k_cvt<<<((LL*KK*CC*CC) + 255)/256, 256, 0, stream>>>(Wg, Wgb, LL*KK*CC*CC);
    k_wtt<<<((LL*CC*CC*GG) + 255)/256, 256, 0, stream>>>(Wt, WtTb);
    k_h0<<<TT, 256, 0, stream>>>(x, lniw, lnib, Win, bin, H0, Hbt);

    float* Hin = H0; float* Hout = H1;
    for (int l = 0; l < LL; l++) {
        k_gemm<0, CC><<<dim3(TV/64, (KK*CC)/64), 256, 0, stream>>>(
            Wgb + (size_t)l*KK*CC*CC, Hbt, bg + l*KK*CC, Y);
        k_adj<<<TT + GG - 1, 256, 0, stream>>>(
            Y, Al + l*KK*VV*VV, ln1w + l*CC*VV, ln1b + l*CC*VV, Ut);
        k_gemm<1, CC*GG><<<dim3(TV/64, CC/64), 256, 0, stream>>>(
            WtTb + (size_t)l*CC*CC*GG, Ut, bt + l*CC, TC);
        k_ln2<<<TT, 256, 0, stream>>>(
            TC, ln2w + l*CC*VV, ln2b + l*CC*VV, Hin, Hout, Hbt);
        float* tmp = Hin; Hin = Hout; Hout = tmp;
    }
    k_out<<<TT, 256, 0, stream>>>(Hin, Wout, bout, out);
}

// Round 3
// 949.006 us; speedup vs baseline: 2.0559x; 1.0835x over previous
//
#include <hip/hip_runtime.h>

#define TT  128
#define CC  256
#define VV  25
#define KK  3
#define GG  9
#define LL  9
#define NCC 60
#define CINN 3
#define TV   (TT*VV)           // 3200
#define KDIM2 (CC*GG)          // 2304
#define HR   (TT*32)           // Hbt2 rows (4096): row = t*32+v, 256 c's each
#define UR   ((TT+8)*32)       // Ut2 rows (4352): row = (t+8)*32+v
#define YSTR 104               // LDS Yt row stride (shorts): 208B = 13*16, aligned

typedef __attribute__((ext_vector_type(8))) short bf16x8;
typedef __attribute__((ext_vector_type(4))) float f32x4;
typedef unsigned short us16;

__device__ __forceinline__ us16 f2bf(float f) {
    union { float f; unsigned u; } a; a.f = f;
    unsigned r = a.u + 0x7fff + ((a.u >> 16) & 1);
    return (us16)(r >> 16);
}
__device__ __forceinline__ bf16x8 ld8(const us16* p) { return *(const bf16x8*)p; }

// ---------------- prep kernels ----------------

__global__ void k_cvt(const float* __restrict__ src, us16* __restrict__ dst, int n) {
    int i = blockIdx.x * 256 + threadIdx.x;
    if (i < n) dst[i] = f2bf(src[i]);
}

// Wt2b[l][o][g*256+c] = bf16(Wt[l][o][c][g])
__global__ void k_wtt(const float* __restrict__ Wt, us16* __restrict__ Wt2b) {
    int i = blockIdx.x * 256 + threadIdx.x;
    if (i >= LL*CC*CC*GG) return;
    int kk = i % (CC*GG);
    int o  = (i / (CC*GG)) % CC;
    int l  = i / (CC*CC*GG);
    int g = kk >> 8, c = kk & 255;
    Wt2b[i] = f2bf(Wt[((size_t)(l*CC + o)*CC + c)*GG + g]);
}

// AlTb[l][k][w][v] = bf16(A[k][v][w]*imp[l][k][v][w]), zero-padded to 32x32
__global__ void k_alt(const float* __restrict__ A, const float* __restrict__ imp,
                      us16* __restrict__ AlTb) {
    int i = blockIdx.x * 256 + threadIdx.x;
    if (i >= LL*KK*32*32) return;
    int v = i & 31, w = (i >> 5) & 31;
    int lk = i >> 10, k = lk % KK, l = lk / KK;
    float val = 0.f;
    if (v < VV && w < VV)
        val = A[(k*VV+v)*VV + w] * imp[((size_t)(l*KK+k)*VV+v)*VV + w];
    AlTb[i] = f2bf(val);
}

// bgAl[l][c][w] = sum_k bg[l][k*256+c] * sum_v Al[l][k][v][w]   (w padded to 32)
__global__ void k_bgal(const float* __restrict__ A, const float* __restrict__ imp,
                       const float* __restrict__ bg, float* __restrict__ bgAl) {
    int i = blockIdx.x * 256 + threadIdx.x;
    if (i >= LL*CC*32) return;
    int w = i & 31, c = (i >> 5) & 255, l = i >> 13;
    float s = 0.f;
    if (w < VV) {
        for (int k = 0; k < KK; k++) {
            float col = 0.f;
            for (int v = 0; v < VV; v++)
                col += A[(k*VV+v)*VV + w] * imp[((size_t)(l*KK+k)*VV+v)*VV + w];
            s += bg[l*KK*CC + k*CC + c] * col;
        }
    }
    bgAl[i] = s;
}

// ---------------- input stage: LN_in + fcn_in ----------------

__global__ __launch_bounds__(256) void k_h0(const float* __restrict__ x,
                                            const float* __restrict__ lnw,
                                            const float* __restrict__ lnb,
                                            const float* __restrict__ Win,
                                            const float* __restrict__ bin,
                                            float* __restrict__ H,
                                            us16* __restrict__ Hbt2) {
    int t = blockIdx.x, tid = threadIdx.x;
    __shared__ float sx[CINN*VV];
    __shared__ float sh[CINN*VV];
    if (tid < CINN*VV)
        sx[tid] = x[(size_t)(tid/VV)*TV + t*VV + (tid%VV)];
    __syncthreads();
    float s = 0.f, q = 0.f;
    for (int i = 0; i < CINN*VV; i++) { float v = sx[i]; s += v; q += v*v; }
    float m  = s * (1.f/75.f);
    float var = q * (1.f/75.f) - m*m;
    float rs = rsqrtf(var + 1e-5f);
    if (tid < CINN*VV)
        sh[tid] = (sx[tid]-m)*rs*lnw[tid] + lnb[tid];
    __syncthreads();
    int c = tid;
    float w0 = Win[c*3+0], w1 = Win[c*3+1], w2 = Win[c*3+2], b = bin[c];
    #pragma unroll
    for (int v = 0; v < VV; v++) {
        float acc = b + w0*sh[v] + w1*sh[VV+v] + w2*sh[2*VV+v];
        H[(size_t)c*TV + t*VV + v] = acc;
        Hbt2[(size_t)(t*32 + v)*CC + c] = f2bf(acc);
    }
    #pragma unroll
    for (int v = VV; v < 32; v++)
        Hbt2[(size_t)(t*32 + v)*CC + c] = 0;
}

// ---------------- block reduce (sum, sumsq) ----------------

__device__ __forceinline__ void blk_reduce2(float& s, float& q, float* red) {
    #pragma unroll
    for (int off = 32; off; off >>= 1) {
        s += __shfl_down(s, off);
        q += __shfl_down(q, off);
    }
    int lane = threadIdx.x & 63, w = threadIdx.x >> 6;
    if (lane == 0) { red[w] = s; red[4+w] = q; }
    __syncthreads();
    s = red[0]+red[1]+red[2]+red[3];
    q = red[4]+red[5]+red[6]+red[7];
}

// ---------------- fused gcn: Y=Wg*H (MFMA) -> adjacency (MFMA) -> LN1 -> ReLU -> Ut2 ----------------

__global__ __launch_bounds__(256, 1) void k_gcn(const us16* __restrict__ Wgb,
                                                const us16* __restrict__ Hbt2,
                                                const us16* __restrict__ AlTb,
                                                const float* __restrict__ bgAl,
                                                const float* __restrict__ lnw,
                                                const float* __restrict__ lnb,
                                                us16* __restrict__ Ut2) {
    int t = blockIdx.x, tid = threadIdx.x;
    if (t >= TT) {                    // 8 history pad frames: relu(ln1_b), zero v-pad
        int tp = t - TT, c = tid;
        #pragma unroll
        for (int w = 0; w < 32; w++) {
            float u = (w < VV) ? fmaxf(lnb[c*VV + w], 0.f) : 0.f;
            Ut2[(size_t)(tp*32 + w)*CC + c] = f2bf(u);
        }
        return;
    }
    __shared__ us16 Yt[CC*YSTR];      // 53.2 KB
    __shared__ float red[8];
    const int wave = tid >> 6, lane = tid & 63, quad = lane >> 4, l16 = lane & 15;

    // ---- phase 1: Y = Wg @ H  (M=768, N=32, K=256) ----
    bf16x8 bf[2][8];
    #pragma unroll
    for (int nt = 0; nt < 2; nt++)
        #pragma unroll
        for (int s = 0; s < 8; s++)
            bf[nt][s] = ld8(Hbt2 + (size_t)(t*32 + nt*16 + l16)*CC + s*32 + quad*8);
    f32x4 acc[12][2];
    #pragma unroll
    for (int mt = 0; mt < 12; mt++) { acc[mt][0] = (f32x4){}; acc[mt][1] = (f32x4){}; }
    #pragma unroll
    for (int mt = 0; mt < 12; mt++) {
        const us16* ap = Wgb + (size_t)(wave*192 + mt*16 + l16)*CC + quad*8;
        #pragma unroll
        for (int s = 0; s < 8; s++) {
            bf16x8 a = ld8(ap + s*32);
            acc[mt][0] = __builtin_amdgcn_mfma_f32_16x16x32_bf16(a, bf[0][s], acc[mt][0], 0,0,0);
            acc[mt][1] = __builtin_amdgcn_mfma_f32_16x16x32_bf16(a, bf[1][s], acc[mt][1], 0,0,0);
        }
    }
    #pragma unroll
    for (int mt = 0; mt < 12; mt++)
        #pragma unroll
        for (int nt = 0; nt < 2; nt++)
            #pragma unroll
            for (int r = 0; r < 4; r++) {
                int m = wave*192 + mt*16 + quad*4 + r;
                Yt[(m & 255)*YSTR + (m >> 8)*32 + nt*16 + l16] = f2bf(acc[mt][nt][r]);
            }
    __syncthreads();

    // ---- phase 2: Z[c][w] = sum_{k,v} Yt[c][k*32+v] * Al[k][v][w]  (M=256,N=32,K=96) ----
    bf16x8 al[2][3];
    #pragma unroll
    for (int nt = 0; nt < 2; nt++)
        #pragma unroll
        for (int s = 0; s < 3; s++)
            al[nt][s] = ld8(AlTb + (size_t)(s*32 + nt*16 + l16)*32 + quad*8);
    f32x4 z[4][2];
    #pragma unroll
    for (int mt = 0; mt < 4; mt++) { z[mt][0] = (f32x4){}; z[mt][1] = (f32x4){}; }
    #pragma unroll
    for (int mt = 0; mt < 4; mt++)
        #pragma unroll
        for (int s = 0; s < 3; s++) {
            bf16x8 a = *(const bf16x8*)(Yt + (wave*64 + mt*16 + l16)*YSTR + s*32 + quad*8);
            z[mt][0] = __builtin_amdgcn_mfma_f32_16x16x32_bf16(a, al[0][s], z[mt][0], 0,0,0);
            z[mt][1] = __builtin_amdgcn_mfma_f32_16x16x32_bf16(a, al[1][s], z[mt][1], 0,0,0);
        }

    // bias fold + LN1 stats over (c,w<25)
    float s_ = 0.f, q_ = 0.f;
    #pragma unroll
    for (int mt = 0; mt < 4; mt++)
        #pragma unroll
        for (int nt = 0; nt < 2; nt++)
            #pragma unroll
            for (int r = 0; r < 4; r++) {
                int c = wave*64 + mt*16 + quad*4 + r;
                int w = nt*16 + l16;
                float zb = z[mt][nt][r] + bgAl[c*32 + w];
                z[mt][nt][r] = zb;
                if (w < VV) { s_ += zb; q_ += zb*zb; }
            }
    blk_reduce2(s_, q_, red);
    float m = s_ * (1.f/6400.f);
    float var = q_ * (1.f/6400.f) - m*m;
    float rs = rsqrtf(var + 1e-5f);
    #pragma unroll
    for (int mt = 0; mt < 4; mt++)
        #pragma unroll
        for (int nt = 0; nt < 2; nt++) {
            int w = nt*16 + l16;
            if (w < VV) {
                int c0 = wave*64 + mt*16 + quad*4;
                ushort4 pk;
                float u0 = fmaxf((z[mt][nt][0]-m)*rs*lnw[(c0+0)*VV+w] + lnb[(c0+0)*VV+w], 0.f);
                float u1 = fmaxf((z[mt][nt][1]-m)*rs*lnw[(c0+1)*VV+w] + lnb[(c0+1)*VV+w], 0.f);
                float u2 = fmaxf((z[mt][nt][2]-m)*rs*lnw[(c0+2)*VV+w] + lnb[(c0+2)*VV+w], 0.f);
                float u3 = fmaxf((z[mt][nt][3]-m)*rs*lnw[(c0+3)*VV+w] + lnb[(c0+3)*VV+w], 0.f);
                pk.x = f2bf(u0); pk.y = f2bf(u1); pk.z = f2bf(u2); pk.w = f2bf(u3);
                *(ushort4*)(Ut2 + (size_t)((t+8)*32 + w)*CC + c0) = pk;
            }
        }
    #pragma unroll
    for (int r = VV; r < 32; r++)
        Ut2[(size_t)((t+8)*32 + r)*CC + tid] = 0;
}

// ---------------- fused tcn: GEMM2 (MFMA) + bias + LN2 + residual + ReLU ----------------

__global__ __launch_bounds__(256, 1) void k_tcn(const us16* __restrict__ Wt2,
                                                const us16* __restrict__ Ut2,
                                                const float* __restrict__ bt,
                                                const float* __restrict__ lnw,
                                                const float* __restrict__ lnb,
                                                const float* __restrict__ Hin,
                                                float* __restrict__ Hout,
                                                us16* __restrict__ Hbt2) {
    int t = blockIdx.x, tid = threadIdx.x;
    __shared__ float red[8];
    const int wave = tid >> 6, lane = tid & 63, quad = lane >> 4, l16 = lane & 15;
    f32x4 acc[4][2];
    #pragma unroll
    for (int mt = 0; mt < 4; mt++) { acc[mt][0] = (f32x4){}; acc[mt][1] = (f32x4){}; }
    #pragma unroll 2
    for (int k0 = 0; k0 < KDIM2; k0 += 32) {
        int g = k0 >> 8;
        const us16* ub = Ut2 + (size_t)((t + 8 - g)*32)*CC + (k0 & 255) + quad*8;
        bf16x8 b0 = ld8(ub + (size_t)l16*CC);
        bf16x8 b1 = ld8(ub + (size_t)(16 + l16)*CC);
        #pragma unroll
        for (int mt = 0; mt < 4; mt++) {
            bf16x8 a = ld8(Wt2 + (size_t)(wave*64 + mt*16 + l16)*KDIM2 + k0 + quad*8);
            acc[mt][0] = __builtin_amdgcn_mfma_f32_16x16x32_bf16(a, b0, acc[mt][0], 0,0,0);
            acc[mt][1] = __builtin_amdgcn_mfma_f32_16x16x32_bf16(a, b1, acc[mt][1], 0,0,0);
        }
    }
    // bias + stats
    float s_ = 0.f, q_ = 0.f;
    #pragma unroll
    for (int mt = 0; mt < 4; mt++)
        #pragma unroll
        for (int nt = 0; nt < 2; nt++)
            #pragma unroll
            for (int r = 0; r < 4; r++) {
                int c = wave*64 + mt*16 + quad*4 + r;
                int v = nt*16 + l16;
                float val = acc[mt][nt][r] + bt[c];
                acc[mt][nt][r] = val;
                if (v < VV) { s_ += val; q_ += val*val; }
            }
    blk_reduce2(s_, q_, red);
    float m = s_ * (1.f/6400.f);
    float var = q_ * (1.f/6400.f) - m*m;
    float rs = rsqrtf(var + 1e-5f);
    #pragma unroll
    for (int mt = 0; mt < 4; mt++)
        #pragma unroll
        for (int nt = 0; nt < 2; nt++) {
            int v = nt*16 + l16;
            if (v < VV) {
                int c0 = wave*64 + mt*16 + quad*4;
                float o[4];
                #pragma unroll
                for (int r = 0; r < 4; r++) {
                    int c = c0 + r;
                    float res = (t >= 4) ? Hin[(size_t)c*TV + (t-4)*VV + v] : 0.f;
                    o[r] = fmaxf((acc[mt][nt][r]-m)*rs*lnw[c*VV+v] + lnb[c*VV+v] + res, 0.f);
                    Hout[(size_t)c*TV + t*VV + v] = o[r];
                }
                ushort4 pk;
                pk.x = f2bf(o[0]); pk.y = f2bf(o[1]); pk.z = f2bf(o[2]); pk.w = f2bf(o[3]);
                *(ushort4*)(Hbt2 + (size_t)(t*32 + v)*CC + c0) = pk;
            }
        }
    #pragma unroll
    for (int r = VV; r < 32; r++)
        Hbt2[(size_t)(t*32 + r)*CC + tid] = 0;
}

// ---------------- pool + classifier ----------------

__global__ __launch_bounds__(256) void k_out(const float* __restrict__ H,
                                             const float* __restrict__ Wout,
                                             const float* __restrict__ bout,
                                             float* __restrict__ out) {
    int t = blockIdx.x, tid = threadIdx.x;
    __shared__ float sp[CC];
    float s = 0.f;
    for (int v = 0; v < VV; v++) s += H[(size_t)tid*TV + t*VV + v];
    sp[tid] = s * (1.f/VV);
    __syncthreads();
    if (tid < NCC) {
        float acc = bout[tid];
        for (int c = 0; c < CC; c++) acc = fmaf(Wout[tid*CC+c], sp[c], acc);
        out[t*NCC + tid] = acc;
    }
}

// ---------------- launch ----------------

extern "C" void kernel_launch(void* const* d_in, const int* in_sizes, int n_in,
                              void* d_out, int out_size, void* d_ws, size_t ws_size,
                              hipStream_t stream) {
    const float* x    = (const float*)d_in[0];
    const float* A    = (const float*)d_in[1];
    const float* lniw = (const float*)d_in[2];
    const float* lnib = (const float*)d_in[3];
    const float* Win  = (const float*)d_in[4];
    const float* bin  = (const float*)d_in[5];
    const float* Wg   = (const float*)d_in[6];
    const float* bg   = (const float*)d_in[7];
    const float* ln1w = (const float*)d_in[8];
    const float* ln1b = (const float*)d_in[9];
    const float* Wt   = (const float*)d_in[10];
    const float* bt   = (const float*)d_in[11];
    const float* ln2w = (const float*)d_in[12];
    const float* ln2b = (const float*)d_in[13];
    const float* imp  = (const float*)d_in[14];
    const float* Wout = (const float*)d_in[15];
    const float* bout = (const float*)d_in[16];
    float* out = (float*)d_out;

    float* ws = (float*)d_ws;
    size_t off = 0;
    auto alloc = [&](size_t n) { float* p = ws + off; off += (n + 255) & ~(size_t)255; return p; };
    float* H0   = alloc((size_t)CC*TV);
    float* H1   = alloc((size_t)CC*TV);
    float* bgAl = alloc((size_t)LL*CC*32);
    us16* Wgb  = (us16*)alloc((size_t)LL*KK*CC*CC/2);
    us16* Wt2b = (us16*)alloc((size_t)LL*CC*KDIM2/2);
    us16* Hbt2 = (us16*)alloc((size_t)HR*CC/2);
    us16* Ut2  = (us16*)alloc((size_t)UR*CC/2);
    us16* AlTb = (us16*)alloc((size_t)LL*KK*32*32/2);
    (void)ws_size; (void)in_sizes; (void)n_in; (void)out_size;

    k_cvt<<<((LL*KK*CC*CC) + 255)/256, 256, 0, stream>>>(Wg, Wgb, LL*KK*CC*CC);
    k_wtt<<<((LL*CC*CC*GG) + 255)/256, 256, 0, stream>>>(Wt, Wt2b);
    k_alt<<<((LL*KK*32*32) + 255)/256, 256, 0, stream>>>(A, imp, AlTb);
    k_bgal<<<((LL*CC*32) + 255)/256, 256, 0, stream>>>(A, imp, bg, bgAl);
    k_h0<<<TT, 256, 0, stream>>>(x, lniw, lnib, Win, bin, H0, Hbt2);

    float* Hin = H0; float* Hout = H1;
    for (int l = 0; l < LL; l++) {
        k_gcn<<<TT + 8, 256, 0, stream>>>(
            Wgb + (size_t)l*KK*CC*CC, Hbt2, AlTb + (size_t)l*KK*32*32,
            bgAl + (size_t)l*CC*32, ln1w + l*CC*VV, ln1b + l*CC*VV, Ut2);
        k_tcn<<<TT, 256, 0, stream>>>(
            Wt2b + (size_t)l*CC*KDIM2, Ut2, bt + l*CC,
            ln2w + l*CC*VV, ln2b + l*CC*VV, Hin, Hout, Hbt2);
        float* tmp = Hin; Hin = Hout; Hout = tmp;
    }
    k_out<<<TT, 256, 0, stream>>>(Hin, Wout, bout, out);
}

// Round 4
// 867.225 us; speedup vs baseline: 2.2498x; 1.0943x over previous
//
#include <hip/hip_runtime.h>

#define TT  128
#define CC  256
#define VV  25
#define KK  3
#define GG  9
#define LL  9
#define NCC 60
#define CINN 3
#define TV    (TT*VV)          // 3200 (input x layout)
#define N4    4096             // padded activation columns: n = t*32+v
#define KDIM2 (CC*GG)          // 2304
#define UR    ((TT+8)*32)      // 4352 Ut2 rows: row = (t+8)*32+v

typedef __attribute__((ext_vector_type(8))) short bf16x8;
typedef __attribute__((ext_vector_type(4))) float f32x4;
typedef unsigned short us16;

__device__ __forceinline__ us16 f2bf(float f) {
    union { float f; unsigned u; } a; a.f = f;
    unsigned r = a.u + 0x7fff + ((a.u >> 16) & 1);
    return (us16)(r >> 16);
}
__device__ __forceinline__ bf16x8 ld8(const us16* p) { return *(const bf16x8*)p; }

// ---------------- prep kernels ----------------

__global__ void k_cvt(const float* __restrict__ src, us16* __restrict__ dst, int n) {
    int i = blockIdx.x * 256 + threadIdx.x;
    if (i < n) dst[i] = f2bf(src[i]);
}

// Wt2b[l][o][g*256+c] = bf16(Wt[l][o][c][g])
__global__ void k_wtt(const float* __restrict__ Wt, us16* __restrict__ Wt2b) {
    int i = blockIdx.x * 256 + threadIdx.x;
    if (i >= LL*CC*CC*GG) return;
    int kk = i % (CC*GG);
    int o  = (i / (CC*GG)) % CC;
    int l  = i / (CC*CC*GG);
    int g = kk >> 8, c = kk & 255;
    Wt2b[i] = f2bf(Wt[((size_t)(l*CC + o)*CC + c)*GG + g]);
}

// AlTb[l][k][w][v] = bf16(A[k][v][w]*imp[l][k][v][w]), zero-padded to 32x32
__global__ void k_alt(const float* __restrict__ A, const float* __restrict__ imp,
                      us16* __restrict__ AlTb) {
    int i = blockIdx.x * 256 + threadIdx.x;
    if (i >= LL*KK*32*32) return;
    int v = i & 31, w = (i >> 5) & 31;
    int lk = i >> 10, k = lk % KK, l = lk / KK;
    float val = 0.f;
    if (v < VV && w < VV)
        val = A[(k*VV+v)*VV + w] * imp[((size_t)(l*KK+k)*VV+v)*VV + w];
    AlTb[i] = f2bf(val);
}

// bgAl[l][c][w] = sum_k bg[l][k*256+c] * sum_v Al[l][k][v][w]
__global__ void k_bgal(const float* __restrict__ A, const float* __restrict__ imp,
                       const float* __restrict__ bg, float* __restrict__ bgAl) {
    int i = blockIdx.x * 256 + threadIdx.x;
    if (i >= LL*CC*32) return;
    int w = i & 31, c = (i >> 5) & 255, l = i >> 13;
    float s = 0.f;
    if (w < VV) {
        for (int k = 0; k < KK; k++) {
            float col = 0.f;
            for (int v = 0; v < VV; v++)
                col += A[(k*VV+v)*VV + w] * imp[((size_t)(l*KK+k)*VV+v)*VV + w];
            s += bg[l*KK*CC + k*CC + c] * col;
        }
    }
    bgAl[i] = s;
}

// ---------------- input stage: LN_in + fcn_in ----------------

__global__ __launch_bounds__(256) void k_h0(const float* __restrict__ x,
                                            const float* __restrict__ lnw,
                                            const float* __restrict__ lnb,
                                            const float* __restrict__ Win,
                                            const float* __restrict__ bin,
                                            float* __restrict__ H,
                                            us16* __restrict__ Hbt2) {
    int t = blockIdx.x, tid = threadIdx.x;
    __shared__ float sx[CINN*VV];
    __shared__ float sh[CINN*VV];
    if (tid < CINN*VV)
        sx[tid] = x[(size_t)(tid/VV)*TV + t*VV + (tid%VV)];
    __syncthreads();
    float s = 0.f, q = 0.f;
    for (int i = 0; i < CINN*VV; i++) { float v = sx[i]; s += v; q += v*v; }
    float m  = s * (1.f/75.f);
    float var = q * (1.f/75.f) - m*m;
    float rs = rsqrtf(var + 1e-5f);
    if (tid < CINN*VV)
        sh[tid] = (sx[tid]-m)*rs*lnw[tid] + lnb[tid];
    __syncthreads();
    int c = tid;
    float w0 = Win[c*3+0], w1 = Win[c*3+1], w2 = Win[c*3+2], b = bin[c];
    #pragma unroll
    for (int v = 0; v < VV; v++) {
        float acc = b + w0*sh[v] + w1*sh[VV+v] + w2*sh[2*VV+v];
        H[(size_t)c*N4 + t*32 + v] = acc;
        Hbt2[(size_t)(t*32 + v)*CC + c] = f2bf(acc);
    }
    #pragma unroll
    for (int v = VV; v < 32; v++)
        Hbt2[(size_t)(t*32 + v)*CC + c] = 0;
}

// ---------------- block reduce (sum, sumsq) ----------------

__device__ __forceinline__ void blk_reduce2(float& s, float& q, float* red) {
    #pragma unroll
    for (int off = 32; off; off >>= 1) {
        s += __shfl_down(s, off);
        q += __shfl_down(q, off);
    }
    int lane = threadIdx.x & 63, w = threadIdx.x >> 6;
    if (lane == 0) { red[w] = s; red[4+w] = q; }
    __syncthreads();
    s = red[0]+red[1]+red[2]+red[3];
    q = red[4]+red[5]+red[6]+red[7];
}

// ---------------- GEMM1: Y = Wg @ H  (768 x 4096, K=256) -> Ybt[t][c][k*32+v] ----------------

__global__ __launch_bounds__(256) void k_gemm1(const us16* __restrict__ A,
                                               const us16* __restrict__ Bt,
                                               us16* __restrict__ Ybt) {
    const int tid = threadIdx.x;
    const int wave = tid >> 6, lane = tid & 63, quad = lane >> 4, l16 = lane & 15;
    const int m0w = blockIdx.y * 64 + (wave & 1) * 32;
    const int n0w = blockIdx.x * 64 + (wave >> 1) * 32;
    const us16* ap = A + (size_t)(m0w + l16) * CC + quad * 8;
    const us16* bp = Bt + (size_t)(n0w + l16) * CC + quad * 8;
    f32x4 acc[2][2] = {};
    #pragma unroll
    for (int s = 0; s < 8; s++) {
        bf16x8 a0 = ld8(ap + s*32);
        bf16x8 a1 = ld8(ap + s*32 + 16*CC);
        bf16x8 b0 = ld8(bp + s*32);
        bf16x8 b1 = ld8(bp + s*32 + 16*CC);
        acc[0][0] = __builtin_amdgcn_mfma_f32_16x16x32_bf16(a0, b0, acc[0][0], 0,0,0);
        acc[0][1] = __builtin_amdgcn_mfma_f32_16x16x32_bf16(a0, b1, acc[0][1], 0,0,0);
        acc[1][0] = __builtin_amdgcn_mfma_f32_16x16x32_bf16(a1, b0, acc[1][0], 0,0,0);
        acc[1][1] = __builtin_amdgcn_mfma_f32_16x16x32_bf16(a1, b1, acc[1][1], 0,0,0);
    }
    #pragma unroll
    for (int mt = 0; mt < 2; mt++)
        #pragma unroll
        for (int nt = 0; nt < 2; nt++)
            #pragma unroll
            for (int r = 0; r < 4; r++) {
                int m = m0w + mt*16 + quad*4 + r;
                int n = n0w + nt*16 + l16;
                int k = m >> 8, c = m & 255;
                int t = n >> 5, v = n & 31;
                Ybt[((size_t)(t*CC + c))*96 + k*32 + v] = f2bf(acc[mt][nt][r]);
            }
}

// ---------------- adjacency (MFMA, M=256 N=32 K=96) + LN1 + ReLU -> Ut2 ----------------

__global__ __launch_bounds__(256) void k_adj(const us16* __restrict__ Ybt,
                                             const us16* __restrict__ AlTb,
                                             const float* __restrict__ bgAl,
                                             const float* __restrict__ lnw,
                                             const float* __restrict__ lnb,
                                             us16* __restrict__ Ut2) {
    int t = blockIdx.x, tid = threadIdx.x;
    if (t >= TT) {                    // 8 history pad frames
        int tp = t - TT, c = tid;
        #pragma unroll
        for (int w = 0; w < 32; w++) {
            float u = (w < VV) ? fmaxf(lnb[c*VV + w], 0.f) : 0.f;
            Ut2[(size_t)(tp*32 + w)*CC + c] = f2bf(u);
        }
        return;
    }
    __shared__ float red[8];
    const int wave = tid >> 6, lane = tid & 63, quad = lane >> 4, l16 = lane & 15;
    bf16x8 al[2][3];
    #pragma unroll
    for (int nt = 0; nt < 2; nt++)
        #pragma unroll
        for (int s = 0; s < 3; s++)
            al[nt][s] = ld8(AlTb + (size_t)(s*32 + nt*16 + l16)*32 + quad*8);
    f32x4 z[4][2];
    #pragma unroll
    for (int mt = 0; mt < 4; mt++) { z[mt][0] = (f32x4){}; z[mt][1] = (f32x4){}; }
    #pragma unroll
    for (int mt = 0; mt < 4; mt++) {
        const us16* yp = Ybt + ((size_t)(t*CC + wave*64 + mt*16 + l16))*96 + quad*8;
        #pragma unroll
        for (int s = 0; s < 3; s++) {
            bf16x8 a = ld8(yp + s*32);
            z[mt][0] = __builtin_amdgcn_mfma_f32_16x16x32_bf16(a, al[0][s], z[mt][0], 0,0,0);
            z[mt][1] = __builtin_amdgcn_mfma_f32_16x16x32_bf16(a, al[1][s], z[mt][1], 0,0,0);
        }
    }
    float s_ = 0.f, q_ = 0.f;
    #pragma unroll
    for (int mt = 0; mt < 4; mt++)
        #pragma unroll
        for (int nt = 0; nt < 2; nt++)
            #pragma unroll
            for (int r = 0; r < 4; r++) {
                int c = wave*64 + mt*16 + quad*4 + r;
                int w = nt*16 + l16;
                float zb = z[mt][nt][r] + bgAl[c*32 + w];
                z[mt][nt][r] = zb;
                if (w < VV) { s_ += zb; q_ += zb*zb; }
            }
    blk_reduce2(s_, q_, red);
    float m = s_ * (1.f/6400.f);
    float var = q_ * (1.f/6400.f) - m*m;
    float rs = rsqrtf(var + 1e-5f);
    #pragma unroll
    for (int mt = 0; mt < 4; mt++)
        #pragma unroll
        for (int nt = 0; nt < 2; nt++) {
            int w = nt*16 + l16;
            if (w < VV) {
                int c0 = wave*64 + mt*16 + quad*4;
                ushort4 pk;
                float u0 = fmaxf((z[mt][nt][0]-m)*rs*lnw[(c0+0)*VV+w] + lnb[(c0+0)*VV+w], 0.f);
                float u1 = fmaxf((z[mt][nt][1]-m)*rs*lnw[(c0+1)*VV+w] + lnb[(c0+1)*VV+w], 0.f);
                float u2 = fmaxf((z[mt][nt][2]-m)*rs*lnw[(c0+2)*VV+w] + lnb[(c0+2)*VV+w], 0.f);
                float u3 = fmaxf((z[mt][nt][3]-m)*rs*lnw[(c0+3)*VV+w] + lnb[(c0+3)*VV+w], 0.f);
                pk.x = f2bf(u0); pk.y = f2bf(u1); pk.z = f2bf(u2); pk.w = f2bf(u3);
                *(ushort4*)(Ut2 + (size_t)((t+8)*32 + w)*CC + c0) = pk;
            }
        }
    #pragma unroll
    for (int r = VV; r < 32; r++)
        Ut2[(size_t)((t+8)*32 + r)*CC + tid] = 0;
}

// ---------------- GEMM2: TC = Wt2 @ Ushift  (256 x 4096, K=2304), register-pipelined ----------------

__global__ __launch_bounds__(256) void k_gemm2(const us16* __restrict__ A,
                                               const us16* __restrict__ Ut2,
                                               float* __restrict__ TC) {
    const int tid = threadIdx.x;
    const int wave = tid >> 6, lane = tid & 63, quad = lane >> 4, l16 = lane & 15;
    const int m0w = blockIdx.y * 64 + (wave & 1) * 32;
    const int n0w = blockIdx.x * 64 + (wave >> 1) * 32;
    const us16* ap = A + (size_t)(m0w + l16) * KDIM2 + quad * 8;
    f32x4 acc00 = {}, acc01 = {}, acc10 = {}, acc11 = {};
    bf16x8 a0, a1, b0, b1;

    auto loadAB = [&](int k0, bf16x8& x0, bf16x8& x1, bf16x8& y0, bf16x8& y1) {
        x0 = ld8(ap + k0);
        x1 = ld8(ap + k0 + 16*KDIM2);
        int g = k0 >> 8;
        const us16* bp = Ut2 + (size_t)(n0w + (8-g)*32 + l16)*CC + (k0 & 255) + quad*8;
        y0 = ld8(bp);
        y1 = ld8(bp + 16*CC);
    };
    loadAB(0, a0, a1, b0, b1);
    #pragma unroll 4
    for (int k0 = 32; k0 < KDIM2; k0 += 32) {
        bf16x8 c0, c1, d0, d1;
        loadAB(k0, c0, c1, d0, d1);
        acc00 = __builtin_amdgcn_mfma_f32_16x16x32_bf16(a0, b0, acc00, 0,0,0);
        acc01 = __builtin_amdgcn_mfma_f32_16x16x32_bf16(a0, b1, acc01, 0,0,0);
        acc10 = __builtin_amdgcn_mfma_f32_16x16x32_bf16(a1, b0, acc10, 0,0,0);
        acc11 = __builtin_amdgcn_mfma_f32_16x16x32_bf16(a1, b1, acc11, 0,0,0);
        a0 = c0; a1 = c1; b0 = d0; b1 = d1;
    }
    acc00 = __builtin_amdgcn_mfma_f32_16x16x32_bf16(a0, b0, acc00, 0,0,0);
    acc01 = __builtin_amdgcn_mfma_f32_16x16x32_bf16(a0, b1, acc01, 0,0,0);
    acc10 = __builtin_amdgcn_mfma_f32_16x16x32_bf16(a1, b0, acc10, 0,0,0);
    acc11 = __builtin_amdgcn_mfma_f32_16x16x32_bf16(a1, b1, acc11, 0,0,0);

    const int r0 = m0w + quad*4;
    const int col = n0w + l16;
    #pragma unroll
    for (int r = 0; r < 4; r++) {
        TC[(size_t)(r0 + r)*N4 + col]           = acc00[r];
        TC[(size_t)(r0 + r)*N4 + col + 16]      = acc01[r];
        TC[(size_t)(r0 + 16 + r)*N4 + col]      = acc10[r];
        TC[(size_t)(r0 + 16 + r)*N4 + col + 16] = acc11[r];
    }
}

// ---------------- LN2 + bias + delayed residual + ReLU ----------------

__global__ __launch_bounds__(256) void k_ln2(const float* __restrict__ TC,
                                             const float* __restrict__ bt,
                                             const float* __restrict__ lnw,
                                             const float* __restrict__ lnb,
                                             const float* __restrict__ Hin,
                                             float* __restrict__ Hout,
                                             us16* __restrict__ Hbt2) {
    int t = blockIdx.x, tid = threadIdx.x;
    __shared__ float sv[CC*33];
    __shared__ float red[8];
    // coalesced load of the frame's 256x32 slab into LDS
    #pragma unroll
    for (int j = 0; j < 8; j++) {
        int c = j*32 + (tid >> 3);
        int v4 = (tid & 7) * 4;
        float4 x = *(const float4*)(TC + (size_t)c*N4 + t*32 + v4);
        sv[c*33 + v4+0] = x.x; sv[c*33 + v4+1] = x.y;
        sv[c*33 + v4+2] = x.z; sv[c*33 + v4+3] = x.w;
    }
    __syncthreads();
    int c = tid;
    float btc = bt[c];
    float vals[VV];
    float s = 0.f, q = 0.f;
    #pragma unroll
    for (int v = 0; v < VV; v++) {
        float x = sv[c*33 + v] + btc;
        vals[v] = x; s += x; q += x*x;
    }
    blk_reduce2(s, q, red);
    float m = s * (1.f/6400.f);
    float var = q * (1.f/6400.f) - m*m;
    float rs = rsqrtf(var + 1e-5f);
    __syncthreads();
    #pragma unroll
    for (int v = 0; v < VV; v++) {
        float res = (t >= 4) ? Hin[(size_t)c*N4 + (t-4)*32 + v] : 0.f;
        float o = fmaxf((vals[v]-m)*rs*lnw[c*VV+v] + lnb[c*VV+v] + res, 0.f);
        Hout[(size_t)c*N4 + t*32 + v] = o;
        sv[c*33 + v] = o;
    }
    __syncthreads();
    #pragma unroll
    for (int v = 0; v < VV; v++)
        Hbt2[(size_t)(t*32 + v)*CC + tid] = f2bf(sv[tid*33 + v]);
    #pragma unroll
    for (int v = VV; v < 32; v++)
        Hbt2[(size_t)(t*32 + v)*CC + tid] = 0;
}

// ---------------- pool + classifier ----------------

__global__ __launch_bounds__(256) void k_out(const float* __restrict__ H,
                                             const float* __restrict__ Wout,
                                             const float* __restrict__ bout,
                                             float* __restrict__ out) {
    int t = blockIdx.x, tid = threadIdx.x;
    __shared__ float sp[CC];
    float s = 0.f;
    for (int v = 0; v < VV; v++) s += H[(size_t)tid*N4 + t*32 + v];
    sp[tid] = s * (1.f/VV);
    __syncthreads();
    if (tid < NCC) {
        float acc = bout[tid];
        for (int c = 0; c < CC; c++) acc = fmaf(Wout[tid*CC+c], sp[c], acc);
        out[t*NCC + tid] = acc;
    }
}

// ---------------- launch ----------------

extern "C" void kernel_launch(void* const* d_in, const int* in_sizes, int n_in,
                              void* d_out, int out_size, void* d_ws, size_t ws_size,
                              hipStream_t stream) {
    const float* x    = (const float*)d_in[0];
    const float* A    = (const float*)d_in[1];
    const float* lniw = (const float*)d_in[2];
    const float* lnib = (const float*)d_in[3];
    const float* Win  = (const float*)d_in[4];
    const float* bin  = (const float*)d_in[5];
    const float* Wg   = (const float*)d_in[6];
    const float* bg   = (const float*)d_in[7];
    const float* ln1w = (const float*)d_in[8];
    const float* ln1b = (const float*)d_in[9];
    const float* Wt   = (const float*)d_in[10];
    const float* bt   = (const float*)d_in[11];
    const float* ln2w = (const float*)d_in[12];
    const float* ln2b = (const float*)d_in[13];
    const float* imp  = (const float*)d_in[14];
    const float* Wout = (const float*)d_in[15];
    const float* bout = (const float*)d_in[16];
    float* out = (float*)d_out;

    float* ws = (float*)d_ws;
    size_t off = 0;
    auto alloc = [&](size_t n) { float* p = ws + off; off += (n + 255) & ~(size_t)255; return p; };
    float* H0   = alloc((size_t)CC*N4);
    float* H1   = alloc((size_t)CC*N4);
    float* TC   = alloc((size_t)CC*N4);
    float* bgAl = alloc((size_t)LL*CC*32);
    us16* Wgb  = (us16*)alloc((size_t)LL*KK*CC*CC/2);
    us16* Wt2b = (us16*)alloc((size_t)LL*CC*KDIM2/2);
    us16* Hbt2 = (us16*)alloc((size_t)N4*CC/2);
    us16* Ut2  = (us16*)alloc((size_t)UR*CC/2);
    us16* AlTb = (us16*)alloc((size_t)LL*KK*32*32/2);
    us16* Ybt  = (us16*)alloc((size_t)TT*CC*96/2);
    (void)ws_size; (void)in_sizes; (void)n_in; (void)out_size;

    k_cvt<<<((LL*KK*CC*CC) + 255)/256, 256, 0, stream>>>(Wg, Wgb, LL*KK*CC*CC);
    k_wtt<<<((LL*CC*CC*GG) + 255)/256, 256, 0, stream>>>(Wt, Wt2b);
    k_alt<<<((LL*KK*32*32) + 255)/256, 256, 0, stream>>>(A, imp, AlTb);
    k_bgal<<<((LL*CC*32) + 255)/256, 256, 0, stream>>>(A, imp, bg, bgAl);
    k_h0<<<TT, 256, 0, stream>>>(x, lniw, lnib, Win, bin, H0, Hbt2);

    float* Hin = H0; float* Hout = H1;
    for (int l = 0; l < LL; l++) {
        k_gemm1<<<dim3(N4/64, (KK*CC)/64), 256, 0, stream>>>(
            Wgb + (size_t)l*KK*CC*CC, Hbt2, Ybt);
        k_adj<<<TT + 8, 256, 0, stream>>>(
            Ybt, AlTb + (size_t)l*KK*32*32, bgAl + (size_t)l*CC*32,
            ln1w + l*CC*VV, ln1b + l*CC*VV, Ut2);
        k_gemm2<<<dim3(N4/64, CC/64), 256, 0, stream>>>(
            Wt2b + (size_t)l*CC*KDIM2, Ut2, TC);
        k_ln2<<<TT, 256, 0, stream>>>(
            TC, bt + l*CC, ln2w + l*CC*VV, ln2b + l*CC*VV, Hin, Hout, Hbt2);
        float* tmp = Hin; Hin = Hout; Hout = tmp;
    }
    k_out<<<TT, 256, 0, stream>>>(Hin, Wout, bout, out);
}